// Round 3
// baseline (107.589 us; speedup 1.0000x reference)
//
#include <hip/hip_runtime.h>
#include <hip/hip_cooperative_groups.h>

namespace cg = cooperative_groups;

// CenterLoss: loss = sum(clip(distmat * onehot_mask, 1e-12, 1e12)) / B
// Only distmat[b, labels[b]] survives the mask; the (B*C - B) exact zeros
// each clamp to 1e-12 -> closed-form constant. So: per-row squared distance
// x[b] vs centers[labels[b]], clamp per row, sum, + constant, / B.
//
// Single cooperative kernel (one graph node, no memset, no atomics):
// 256 blocks x 256 threads, 16 rows/block; block partial -> d_ws;
// grid.sync(); block 0 reduces 256 partials and writes out[0].

#define BATCH 4096
#define DIM 512
#define NUM_CLASSES 10000
#define ROWS_PER_WAVE 4
#define WAVES_PER_BLOCK 4
#define ROWS_PER_BLOCK (ROWS_PER_WAVE * WAVES_PER_BLOCK)   // 16
#define NUM_BLOCKS (BATCH / ROWS_PER_BLOCK)                // 256

__global__ __launch_bounds__(256) void center_loss_coop(
    const float* __restrict__ x,
    const int* __restrict__ labels,
    const float* __restrict__ centers,
    float* __restrict__ out,
    float* __restrict__ partials)
{
    const int wave = threadIdx.x >> 6;   // 0..3
    const int lane = threadIdx.x & 63;   // 0..63
    const int row0 = blockIdx.x * ROWS_PER_BLOCK + wave * ROWS_PER_WAVE;

    // 16 independent 16B loads per lane — deep outstanding-load ILP.
    float4 a[ROWS_PER_WAVE][2], b[ROWS_PER_WAVE][2];
    #pragma unroll
    for (int r = 0; r < ROWS_PER_WAVE; ++r) {
        const int row = row0 + r;
        const int lbl = labels[row];                       // wave-uniform -> scalar
        const float4* xp = (const float4*)(x + (size_t)row * DIM);
        const float4* cp = (const float4*)(centers + (size_t)lbl * DIM);
        a[r][0] = xp[lane];
        a[r][1] = xp[lane + 64];
        b[r][0] = cp[lane];
        b[r][1] = cp[lane + 64];
    }

    float acc[ROWS_PER_WAVE];
    #pragma unroll
    for (int r = 0; r < ROWS_PER_WAVE; ++r) {
        float d, s = 0.0f;
        d = a[r][0].x - b[r][0].x; s += d * d;
        d = a[r][0].y - b[r][0].y; s += d * d;
        d = a[r][0].z - b[r][0].z; s += d * d;
        d = a[r][0].w - b[r][0].w; s += d * d;
        d = a[r][1].x - b[r][1].x; s += d * d;
        d = a[r][1].y - b[r][1].y; s += d * d;
        d = a[r][1].z - b[r][1].z; s += d * d;
        d = a[r][1].w - b[r][1].w; s += d * d;
        acc[r] = s;
    }

    // wave-64 shuffle reduction, 4 rows through the same tree
    #pragma unroll
    for (int off = 32; off > 0; off >>= 1) {
        #pragma unroll
        for (int r = 0; r < ROWS_PER_WAVE; ++r)
            acc[r] += __shfl_down(acc[r], off, 64);
    }

    __shared__ float s_wave[WAVES_PER_BLOCK];
    if (lane == 0) {
        // clamp is per matrix entry, i.e. per row distance
        float w = 0.0f;
        #pragma unroll
        for (int r = 0; r < ROWS_PER_WAVE; ++r)
            w += fminf(fmaxf(acc[r], 1e-12f), 1e12f);
        s_wave[wave] = w;
    }
    __syncthreads();
    if (threadIdx.x == 0)
        partials[blockIdx.x] = s_wave[0] + s_wave[1] + s_wave[2] + s_wave[3];

    cg::this_grid().sync();

    if (blockIdx.x == 0) {
        float acc2 = (threadIdx.x < NUM_BLOCKS) ? partials[threadIdx.x] : 0.0f;
        #pragma unroll
        for (int off = 32; off > 0; off >>= 1)
            acc2 += __shfl_down(acc2, off, 64);

        __shared__ float s2[WAVES_PER_BLOCK];
        if (lane == 0) s2[wave] = acc2;
        __syncthreads();
        if (threadIdx.x == 0) {
            double total = (double)s2[0] + (double)s2[1] + (double)s2[2] + (double)s2[3];
            // (B*C - B) zero entries clamped to 1e-12
            total += (double)BATCH * (double)(NUM_CLASSES - 1) * 1e-12;
            out[0] = (float)(total / (double)BATCH);
        }
    }
}

extern "C" void kernel_launch(void* const* d_in, const int* in_sizes, int n_in,
                              void* d_out, int out_size, void* d_ws, size_t ws_size,
                              hipStream_t stream) {
    const float* x       = (const float*)d_in[0];   // (4096, 512) f32
    const int*   labels  = (const int*)d_in[1];     // (4096,) int
    const float* centers = (const float*)d_in[2];   // (10000, 512) f32
    float* out   = (float*)d_out;                   // scalar loss
    float* parts = (float*)d_ws;                    // NUM_BLOCKS floats

    void* args[] = { (void*)&x, (void*)&labels, (void*)&centers,
                     (void*)&out, (void*)&parts };
    hipLaunchCooperativeKernel((void*)center_loss_coop,
                               dim3(NUM_BLOCKS), dim3(256), args, 0, stream);
}

// Round 4
// 74.143 us; speedup vs baseline: 1.4511x; 1.4511x over previous
//
#include <hip/hip_runtime.h>

// CenterLoss: loss = sum(clip(distmat * onehot_mask, 1e-12, 1e12)) / B
// Only distmat[b, labels[b]] survives the mask; the (B*C - B) exact zeros
// each clamp to 1e-12 -> closed-form constant. So: per-row squared distance
// x[b] vs centers[labels[b]], clamp per row, sum, + constant, / B.
//
// Best-measured structure (R1, 74.0 us) + R2 polish: two plain kernel
// nodes (cooperative launch regressed +31 us in R3; memset+atomic was
// neutral). Kernel 1: 256 blocks x 256 threads, 16 rows/block (16
// independent float4 loads/lane -> deep VMEM ILP), per-row clamp, block
// LDS reduce -> 256 partials in d_ws. Kernel 2: one wave reduces 256.

#define BATCH 4096
#define DIM 512
#define NUM_CLASSES 10000
#define ROWS_PER_WAVE 4
#define WAVES_PER_BLOCK 4
#define ROWS_PER_BLOCK (ROWS_PER_WAVE * WAVES_PER_BLOCK)   // 16
#define NUM_BLOCKS (BATCH / ROWS_PER_BLOCK)                // 256

__global__ __launch_bounds__(256) void center_loss_partial(
    const float* __restrict__ x,
    const int* __restrict__ labels,
    const float* __restrict__ centers,
    float* __restrict__ partials)
{
    const int wave = threadIdx.x >> 6;   // 0..3
    const int lane = threadIdx.x & 63;   // 0..63
    const int row0 = blockIdx.x * ROWS_PER_BLOCK + wave * ROWS_PER_WAVE;

    // 16 independent 16B loads per lane — deep outstanding-load ILP.
    float4 a[ROWS_PER_WAVE][2], b[ROWS_PER_WAVE][2];
    #pragma unroll
    for (int r = 0; r < ROWS_PER_WAVE; ++r) {
        const int row = row0 + r;
        const int lbl = labels[row];                       // wave-uniform -> scalar
        const float4* xp = (const float4*)(x + (size_t)row * DIM);
        const float4* cp = (const float4*)(centers + (size_t)lbl * DIM);
        a[r][0] = xp[lane];
        a[r][1] = xp[lane + 64];
        b[r][0] = cp[lane];
        b[r][1] = cp[lane + 64];
    }

    float acc[ROWS_PER_WAVE];
    #pragma unroll
    for (int r = 0; r < ROWS_PER_WAVE; ++r) {
        float d, s = 0.0f;
        d = a[r][0].x - b[r][0].x; s += d * d;
        d = a[r][0].y - b[r][0].y; s += d * d;
        d = a[r][0].z - b[r][0].z; s += d * d;
        d = a[r][0].w - b[r][0].w; s += d * d;
        d = a[r][1].x - b[r][1].x; s += d * d;
        d = a[r][1].y - b[r][1].y; s += d * d;
        d = a[r][1].z - b[r][1].z; s += d * d;
        d = a[r][1].w - b[r][1].w; s += d * d;
        acc[r] = s;
    }

    // wave-64 shuffle reduction, 4 rows through the same tree
    #pragma unroll
    for (int off = 32; off > 0; off >>= 1) {
        #pragma unroll
        for (int r = 0; r < ROWS_PER_WAVE; ++r)
            acc[r] += __shfl_down(acc[r], off, 64);
    }

    __shared__ float s_wave[WAVES_PER_BLOCK];
    if (lane == 0) {
        // clamp is per matrix entry, i.e. per row distance
        float w = 0.0f;
        #pragma unroll
        for (int r = 0; r < ROWS_PER_WAVE; ++r)
            w += fminf(fmaxf(acc[r], 1e-12f), 1e12f);
        s_wave[wave] = w;
    }
    __syncthreads();
    if (threadIdx.x == 0)
        partials[blockIdx.x] = s_wave[0] + s_wave[1] + s_wave[2] + s_wave[3];
}

__global__ __launch_bounds__(64) void center_loss_final(
    const float* __restrict__ partials,
    float* __restrict__ out)
{
    const int lane = threadIdx.x;        // single wave
    float acc = 0.0f;
    #pragma unroll
    for (int i = 0; i < NUM_BLOCKS / 64; ++i)
        acc += partials[lane + i * 64];

    #pragma unroll
    for (int off = 32; off > 0; off >>= 1)
        acc += __shfl_down(acc, off, 64);

    if (lane == 0) {
        double total = (double)acc;
        // (B*C - B) exactly-zero masked entries, each clamped up to 1e-12
        total += (double)BATCH * (double)(NUM_CLASSES - 1) * 1e-12;
        out[0] = (float)(total / (double)BATCH);
    }
}

extern "C" void kernel_launch(void* const* d_in, const int* in_sizes, int n_in,
                              void* d_out, int out_size, void* d_ws, size_t ws_size,
                              hipStream_t stream) {
    const float* x       = (const float*)d_in[0];   // (4096, 512) f32
    const int*   labels  = (const int*)d_in[1];     // (4096,) int
    const float* centers = (const float*)d_in[2];   // (10000, 512) f32
    float* out   = (float*)d_out;                   // scalar loss
    float* parts = (float*)d_ws;                    // NUM_BLOCKS floats

    center_loss_partial<<<NUM_BLOCKS, 256, 0, stream>>>(x, labels, centers, parts);
    center_loss_final<<<1, 64, 0, stream>>>(parts, out);
}